// Round 1
// baseline (534.403 us; speedup 1.0000x reference)
//
#include <hip/hip_runtime.h>

// ManualCrossAttention: B=32,P=512,S=1024,E=512,H=8,D=64
// Pipeline: pack mask -> Q/K/Vt projections (f16 MFMA) -> flash attention -> out proj.
#define B_  32
#define P_  512
#define S_  1024
#define E_  512
#define H_  8
#define D_  64

typedef unsigned int uint32;
typedef unsigned short u16;
typedef __attribute__((ext_vector_type(8))) _Float16 half8;
typedef __attribute__((ext_vector_type(4))) float f32x4;

__device__ __forceinline__ u16 f2h_bits(float f){
  _Float16 h = (_Float16)f;
  union { _Float16 h; u16 u; } cv; cv.h = h; return cv.u;
}
__device__ __forceinline__ half8 cvt8(f32x4 a, f32x4 b){
  half8 h;
  h[0]=(_Float16)a[0]; h[1]=(_Float16)a[1]; h[2]=(_Float16)a[2]; h[3]=(_Float16)a[3];
  h[4]=(_Float16)b[0]; h[5]=(_Float16)b[1]; h[6]=(_Float16)b[2]; h[7]=(_Float16)b[3];
  return h;
}
__device__ __forceinline__ f32x4 mfma16(half8 a, half8 b, f32x4 c){
  return __builtin_amdgcn_mfma_f32_16x16x32_f16(a, b, c, 0, 0, 0);
}

// ---------------- mask dtype detection ----------------
// flag: 0 = 32-bit words 0/1 (int32), 1 = bytes 0/1 (uint8/bool), 2 = other 32-bit (e.g. f32) -> word!=0 test
__global__ void detect_mask_kernel(const uint32* __restrict__ m, int* __restrict__ flag){
  __shared__ int s_gt1, s_bgt1;
  if (threadIdx.x == 0){ s_gt1 = 0; s_bgt1 = 0; }
  __syncthreads();
  int gt1 = 0, bgt1 = 0;
  for (int i = threadIdx.x; i < 4096; i += 256){
    uint32 w = m[i];
    if (w > 1u) gt1 = 1;
    if (((w)&0xffu) > 1u || ((w>>8)&0xffu) > 1u || ((w>>16)&0xffu) > 1u || ((w>>24)&0xffu) > 1u) bgt1 = 1;
  }
  if (gt1)  atomicOr(&s_gt1, 1);
  if (bgt1) atomicOr(&s_bgt1, 1);
  __syncthreads();
  if (threadIdx.x == 0) *flag = s_gt1 ? (s_bgt1 ? 2 : 1) : 0;
}

// pack to bitmask: bit (b*P+p)*S + s  == 1 iff masked (-inf)
__global__ void pack_mask_kernel(const uint32* __restrict__ m, const int* __restrict__ flag,
                                 uint32* __restrict__ bits){
  const int w = blockIdx.x * 256 + threadIdx.x;   // 524288 words total
  const int f = *flag;
  uint32 out = 0u;
  if (f == 1){
    #pragma unroll
    for (int i = 0; i < 8; i++){
      uint32 v = m[(size_t)w*8 + i];
      if (v & 0x000000ffu) out |= 1u << (i*4 + 0);
      if (v & 0x0000ff00u) out |= 1u << (i*4 + 1);
      if (v & 0x00ff0000u) out |= 1u << (i*4 + 2);
      if (v & 0xff000000u) out |= 1u << (i*4 + 3);
    }
  } else {
    #pragma unroll
    for (int i = 0; i < 32; i++){
      if (m[(size_t)w*32 + i]) out |= 1u << i;
    }
  }
  bits[w] = out;
}

// ---------------- GEMM (all K=512, both operands K-contiguous) ----------------
// MODE 0: C[m][n] = sum_k A_f32[m][k]*B_f32[n][k]; store f16 at ((b*8+h)*ROWS + r)*64 + d,
//         b=m>>rshift, r=m&(ROWS-1), h=n>>6, d=n&63.   (Q: rshift=9, K: rshift=10)
// MODE 1: A=Wv (512xK f32), B=value (32768xK f32); store f16 Vt at b*E*S + m*S + s (b=n>>10, s=n&1023)
// MODE 2: A=ctx (f16), B=Wo (f32); store f32 out[m*512+n] + bias[n]
template<int MODE>
__global__ __launch_bounds__(256) void gemm_kernel(
    const void* __restrict__ Ap, const float* __restrict__ Bp,
    void* __restrict__ Cp, const float* __restrict__ bias, int rshift)
{
  __shared__ __align__(16) u16 As[128*72];
  __shared__ __align__(16) u16 Bs[128*72];
  const int tid  = threadIdx.x;
  const int lane = tid & 63;
  const int wv   = tid >> 6;
  const int lrow = lane & 15, khi = lane >> 4;
  const int wm   = wv >> 1,  wn  = wv & 1;
  const long gm0 = (long)blockIdx.y * 128;
  const long gn0 = (long)blockIdx.x * 128;
  const int srow = tid >> 1, scb = (tid & 1) * 32;

  f32x4 acc[4][4];
  #pragma unroll
  for (int i = 0; i < 4; i++)
    #pragma unroll
    for (int j = 0; j < 4; j++) acc[i][j] = (f32x4){0.f,0.f,0.f,0.f};

  #pragma unroll 1
  for (int kk = 0; kk < 512; kk += 64){
    if (kk) __syncthreads();
    if (MODE == 2){
      const u16* ap = (const u16*)Ap + (gm0 + srow)*512 + kk + scb;
      #pragma unroll
      for (int i = 0; i < 4; i++)
        *(half8*)&As[srow*72 + scb + i*8] = *(const half8*)(ap + i*8);
    } else {
      const float* ap = (const float*)Ap + (gm0 + srow)*512 + kk + scb;
      #pragma unroll
      for (int i = 0; i < 4; i++){
        f32x4 f0 = *(const f32x4*)(ap + i*8);
        f32x4 f1 = *(const f32x4*)(ap + i*8 + 4);
        *(half8*)&As[srow*72 + scb + i*8] = cvt8(f0, f1);
      }
    }
    {
      const float* bp = Bp + (gn0 + srow)*512 + kk + scb;
      #pragma unroll
      for (int i = 0; i < 4; i++){
        f32x4 f0 = *(const f32x4*)(bp + i*8);
        f32x4 f1 = *(const f32x4*)(bp + i*8 + 4);
        *(half8*)&Bs[srow*72 + scb + i*8] = cvt8(f0, f1);
      }
    }
    __syncthreads();

    half8 af[4][2], bf[4][2];
    #pragma unroll
    for (int mi = 0; mi < 4; mi++){
      const u16* p = &As[(wm*64 + mi*16 + lrow)*72 + khi*8];
      af[mi][0] = *(const half8*)p;
      af[mi][1] = *(const half8*)(p + 32);
    }
    #pragma unroll
    for (int ni = 0; ni < 4; ni++){
      const u16* p = &Bs[(wn*64 + ni*16 + lrow)*72 + khi*8];
      bf[ni][0] = *(const half8*)p;
      bf[ni][1] = *(const half8*)(p + 32);
    }
    #pragma unroll
    for (int mi = 0; mi < 4; mi++)
      #pragma unroll
      for (int ni = 0; ni < 4; ni++){
        acc[mi][ni] = mfma16(af[mi][0], bf[ni][0], acc[mi][ni]);
        acc[mi][ni] = mfma16(af[mi][1], bf[ni][1], acc[mi][ni]);
      }
  }

  #pragma unroll
  for (int mi = 0; mi < 4; mi++)
    #pragma unroll
    for (int ni = 0; ni < 4; ni++)
      #pragma unroll
      for (int r = 0; r < 4; r++){
        long gm = gm0 + wm*64 + mi*16 + khi*4 + r;
        long gn = gn0 + wn*64 + ni*16 + lrow;
        float v = acc[mi][ni][r];
        if (MODE == 0){
          long b  = gm >> rshift;
          long rr = gm & ((1L << rshift) - 1);
          long h  = gn >> 6, d = gn & 63;
          ((u16*)Cp)[((b*8 + h) << (rshift + 6)) + rr*64 + d] = f2h_bits(v);
        } else if (MODE == 1){
          long b = gn >> 10, s = gn & 1023;
          ((u16*)Cp)[b*524288 + gm*1024 + s] = f2h_bits(v);
        } else {
          ((float*)Cp)[gm*512 + gn] = v + bias[gn];
        }
      }
}

// ---------------- flash attention ----------------
// block = (b,h, 64-row q-tile); 4 waves x 16 q-rows each; s-tiles of 64; online softmax fp32.
__global__ __launch_bounds__(256) void attn_kernel(
    const u16* __restrict__ Qb, const u16* __restrict__ Kb,
    const u16* __restrict__ Vtb, const uint32* __restrict__ bits,
    u16* __restrict__ Ctx)
{
  __shared__ __align__(16) u16 Qs[64*72];
  __shared__ __align__(16) u16 Ks[64*72];
  __shared__ __align__(16) u16 Vs[64*72];
  __shared__ __align__(16) u16 Ps[64*72];
  __shared__ uint32 mlds[64][2];

  const int tid  = threadIdx.x;
  const int lane = tid & 63;
  const int wv   = tid >> 6;
  const int lrow = lane & 15, khi = lane >> 4;
  const int bh = blockIdx.x >> 3;          // b*8+h
  const int p0 = (blockIdx.x & 7) * 64;
  const int bb = bh >> 3;

  const u16* qp = Qb  + (size_t)bh * (P_*64) + (size_t)p0 * 64;
  const u16* kp = Kb  + (size_t)bh * (S_*64);
  const u16* vp = Vtb + (size_t)bh * (D_*S_);

  {
    int row = tid >> 2, cb = (tid & 3) * 16;
    const u16* src = qp + (size_t)row*64 + cb;
    *(half8*)&Qs[row*72 + cb]     = *(const half8*)src;
    *(half8*)&Qs[row*72 + cb + 8] = *(const half8*)(src + 8);
  }
  __syncthreads();
  half8 aq0, aq1;
  {
    const u16* p = &Qs[(wv*16 + lrow)*72 + khi*8];
    aq0 = *(const half8*)p;
    aq1 = *(const half8*)(p + 32);
  }

  f32x4 accO[4];
  #pragma unroll
  for (int i = 0; i < 4; i++) accO[i] = (f32x4){0.f,0.f,0.f,0.f};
  float mst[4], lst[4];
  #pragma unroll
  for (int r = 0; r < 4; r++){ mst[r] = -1e30f; lst[r] = 0.f; }

  #pragma unroll 1
  for (int s0 = 0; s0 < S_; s0 += 64){
    __syncthreads();      // protect K/V/P LDS from previous iteration's readers
    {
      int row = tid >> 2, cb = (tid & 3) * 16;
      const u16* ksrc = kp + (size_t)(s0 + row)*64 + cb;
      *(half8*)&Ks[row*72 + cb]     = *(const half8*)ksrc;
      *(half8*)&Ks[row*72 + cb + 8] = *(const half8*)(ksrc + 8);
      const u16* vsrc = vp + (size_t)row*S_ + s0 + cb;   // Vt rows = d, cols = s
      *(half8*)&Vs[row*72 + cb]     = *(const half8*)vsrc;
      *(half8*)&Vs[row*72 + cb + 8] = *(const half8*)(vsrc + 8);
    }
    if (tid < 128){
      int row = tid >> 1, wsel = tid & 1;
      mlds[row][wsel] = bits[(size_t)(bb*P_ + p0 + row)*(S_/32) + (s0 >> 5) + wsel];
    }
    __syncthreads();

    // QK^T for this wave's 16 rows x 64 cols
    f32x4 sc[4];
    #pragma unroll
    for (int ssub = 0; ssub < 4; ssub++){
      const u16* p = &Ks[(ssub*16 + lrow)*72 + khi*8];
      half8 bk0 = *(const half8*)p;
      half8 bk1 = *(const half8*)(p + 32);
      f32x4 c = (f32x4){0.f,0.f,0.f,0.f};
      c = mfma16(aq0, bk0, c);
      c = mfma16(aq1, bk1, c);
      sc[ssub] = c;
    }

    // scale + mask + online softmax
    float fac[4];
    #pragma unroll
    for (int r = 0; r < 4; r++){
      const int prow = wv*16 + khi*4 + r;
      const uint32 mw0 = mlds[prow][0];
      const uint32 mw1 = mlds[prow][1];
      #pragma unroll
      for (int ssub = 0; ssub < 4; ssub++){
        int sloc = ssub*16 + lrow;
        uint32 mw = (ssub < 2) ? mw0 : mw1;
        float v = sc[ssub][r] * 0.125f;
        if ((mw >> (sloc & 31)) & 1u) v = -1e30f;
        sc[ssub][r] = v;
      }
      float mx = fmaxf(fmaxf(sc[0][r], sc[1][r]), fmaxf(sc[2][r], sc[3][r]));
      #pragma unroll
      for (int off = 1; off < 16; off <<= 1) mx = fmaxf(mx, __shfl_xor(mx, off));
      float mnew = fmaxf(mst[r], mx);
      fac[r] = __expf(mst[r] - mnew);      // both -1e30 -> exp(0)=1: safe, values stay 0
      float ts = 0.f;
      #pragma unroll
      for (int ssub = 0; ssub < 4; ssub++){
        float pv = __expf(sc[ssub][r] - mnew);
        sc[ssub][r] = pv;
        ts += pv;
      }
      #pragma unroll
      for (int off = 1; off < 16; off <<= 1) ts += __shfl_xor(ts, off);
      lst[r] = lst[r]*fac[r] + ts;
      mst[r] = mnew;
    }
    #pragma unroll
    for (int dsub = 0; dsub < 4; dsub++){
      f32x4 a = accO[dsub];
      a[0] *= fac[0]; a[1] *= fac[1]; a[2] *= fac[2]; a[3] *= fac[3];
      accO[dsub] = a;
    }

    // P (f16) -> LDS, then PV
    #pragma unroll
    for (int ssub = 0; ssub < 4; ssub++)
      #pragma unroll
      for (int r = 0; r < 4; r++)
        Ps[(wv*16 + khi*4 + r)*72 + ssub*16 + lrow] = f2h_bits(sc[ssub][r]);
    __syncthreads();

    half8 ap0, ap1;
    {
      const u16* p = &Ps[(wv*16 + lrow)*72 + khi*8];
      ap0 = *(const half8*)p;
      ap1 = *(const half8*)(p + 32);
    }
    #pragma unroll
    for (int dsub = 0; dsub < 4; dsub++){
      const u16* p = &Vs[(dsub*16 + lrow)*72 + khi*8];
      half8 bv0 = *(const half8*)p;
      half8 bv1 = *(const half8*)(p + 32);
      accO[dsub] = mfma16(ap0, bv0, accO[dsub]);
      accO[dsub] = mfma16(ap1, bv1, accO[dsub]);
    }
  }

  const int hh = bh & 7;
  #pragma unroll
  for (int dsub = 0; dsub < 4; dsub++)
    #pragma unroll
    for (int r = 0; r < 4; r++){
      int prow = p0 + wv*16 + khi*4 + r;
      float v = accO[dsub][r] / lst[r];
      Ctx[(size_t)(bb*P_ + prow)*E_ + hh*64 + dsub*16 + lrow] = f2h_bits(v);
    }
}

extern "C" void kernel_launch(void* const* d_in, const int* in_sizes, int n_in,
                              void* d_out, int out_size, void* d_ws, size_t ws_size,
                              hipStream_t stream)
{
  const float* query = (const float*)d_in[0];
  const float* key   = (const float*)d_in[1];
  const float* value = (const float*)d_in[2];
  const void*  mask  = d_in[3];
  const float* Wq = (const float*)d_in[4];
  const float* Wk = (const float*)d_in[5];
  const float* Wv = (const float*)d_in[6];
  const float* Wo = (const float*)d_in[7];
  const float* bo = (const float*)d_in[8];

  char* ws = (char*)d_ws;
  u16*    Qb   = (u16*)(ws);                      // 16 MiB  [b*8+h][p][d] f16
  u16*    Kb   = (u16*)(ws + (16u  << 20));       // 32 MiB  [b*8+h][s][d] f16
  u16*    Vtb  = (u16*)(ws + (48u  << 20));       // 32 MiB  [b*8+h][d][s] f16
  u16*    Ctx  = (u16*)(ws + (80u  << 20));       // 16 MiB  [b*P+p][h*64+d] f16
  uint32* bits = (uint32*)(ws + (96u << 20));     // 2 MiB   packed mask bits
  int*    flag = (int*)(ws + (98u << 20));        // 4 B

  detect_mask_kernel<<<1, 256, 0, stream>>>((const uint32*)mask, flag);
  pack_mask_kernel<<<2048, 256, 0, stream>>>((const uint32*)mask, flag, bits);
  // Q: M=16384 (ROWS=P=512, rshift=9)
  gemm_kernel<0><<<dim3(4, 128), 256, 0, stream>>>((const void*)query, Wq, (void*)Qb, nullptr, 9);
  // K: M=32768 (ROWS=S=1024, rshift=10)
  gemm_kernel<0><<<dim3(4, 256), 256, 0, stream>>>((const void*)key, Wk, (void*)Kb, nullptr, 10);
  // Vt: swapped GEMM, M=512 (Wv rows), N=32768 (value rows)
  gemm_kernel<1><<<dim3(256, 4), 256, 0, stream>>>((const void*)Wv, value, (void*)Vtb, nullptr, 0);
  attn_kernel<<<2048, 256, 0, stream>>>(Qb, Kb, Vtb, bits, Ctx);
  // out = ctx @ Wo^T + bo (fp32)
  gemm_kernel<2><<<dim3(4, 128), 256, 0, stream>>>((const void*)Ctx, Wo, d_out, bo, 0);
}

// Round 6
// 480.768 us; speedup vs baseline: 1.1116x; 1.1116x over previous
//
#include <hip/hip_runtime.h>

// ManualCrossAttention: B=32,P=512,S=1024,E=512,H=8,D=64
// mask pack -> weight cvt (Wq/Wk/Wv only) -> Q/K/Vt projections (f16 MFMA, global_load_lds)
// -> flash attn (XCD-swizzled, XOR-swizzled LDS) -> out proj (A f16 GLD, B f32 reg-stage).
// ws footprint capped at 98 MiB + 4 B (= R0-proven size).
#define B_  32
#define P_  512
#define S_  1024
#define E_  512
#define H_  8
#define D_  64

typedef unsigned int uint32;
typedef unsigned short u16;
typedef __attribute__((ext_vector_type(8))) _Float16 half8;
typedef __attribute__((ext_vector_type(4))) float f32x4;

__device__ __forceinline__ u16 f2h_bits(float f){
  _Float16 h = (_Float16)f;
  union { _Float16 h; u16 u; } cv; cv.h = h; return cv.u;
}
__device__ __forceinline__ half8 cvt8(f32x4 a, f32x4 b){
  half8 h;
  h[0]=(_Float16)a[0]; h[1]=(_Float16)a[1]; h[2]=(_Float16)a[2]; h[3]=(_Float16)a[3];
  h[4]=(_Float16)b[0]; h[5]=(_Float16)b[1]; h[6]=(_Float16)b[2]; h[7]=(_Float16)b[3];
  return h;
}
__device__ __forceinline__ f32x4 mfma16(half8 a, half8 b, f32x4 c){
  return __builtin_amdgcn_mfma_f32_16x16x32_f16(a, b, c, 0, 0, 0);
}
// async global->LDS, 16B per lane. LDS dest must be wave-uniform base + lane*16.
#define GLD16(ldsp, gp) __builtin_amdgcn_global_load_lds( \
    (const __attribute__((address_space(1))) void*)(gp), \
    (__attribute__((address_space(3))) void*)(ldsp), 16, 0, 0)

// ---------------- weight conversion (3 x 512x512 f32 -> f16) ----------------
__global__ void cvt_w_kernel(const float* __restrict__ w0, const float* __restrict__ w1,
                             const float* __restrict__ w2, u16* __restrict__ out){
  int i = blockIdx.x * 256 + threadIdx.x;          // 98304 threads, 8 elems each
  int region = i >> 15;                            // 0..2
  int off = (i & 32767) * 8;
  const float* s = (region == 0) ? w0 : (region == 1) ? w1 : w2;
  f32x4 a = *(const f32x4*)(s + off);
  f32x4 b = *(const f32x4*)(s + off + 4);
  *(half8*)(out + region * 262144 + off) = cvt8(a, b);
}

// ---------------- mask dtype detection ----------------
__global__ void detect_mask_kernel(const uint32* __restrict__ m, int* __restrict__ flag){
  __shared__ int s_gt1, s_bgt1;
  if (threadIdx.x == 0){ s_gt1 = 0; s_bgt1 = 0; }
  __syncthreads();
  int gt1 = 0, bgt1 = 0;
  for (int i = threadIdx.x; i < 4096; i += 256){
    uint32 w = m[i];
    if (w > 1u) gt1 = 1;
    if (((w)&0xffu) > 1u || ((w>>8)&0xffu) > 1u || ((w>>16)&0xffu) > 1u || ((w>>24)&0xffu) > 1u) bgt1 = 1;
  }
  if (gt1)  atomicOr(&s_gt1, 1);
  if (bgt1) atomicOr(&s_bgt1, 1);
  __syncthreads();
  if (threadIdx.x == 0) *flag = s_gt1 ? (s_bgt1 ? 2 : 1) : 0;
}

__global__ void pack_mask_kernel(const uint32* __restrict__ m, const int* __restrict__ flag,
                                 uint32* __restrict__ bits){
  const int w = blockIdx.x * 256 + threadIdx.x;   // 524288 words total
  const int f = *flag;
  uint32 out = 0u;
  if (f == 1){
    #pragma unroll
    for (int i = 0; i < 8; i++){
      uint32 v = m[(size_t)w*8 + i];
      if (v & 0x000000ffu) out |= 1u << (i*4 + 0);
      if (v & 0x0000ff00u) out |= 1u << (i*4 + 1);
      if (v & 0x00ff0000u) out |= 1u << (i*4 + 2);
      if (v & 0xff000000u) out |= 1u << (i*4 + 3);
    }
  } else {
    #pragma unroll
    for (int i = 0; i < 32; i++){
      if (m[(size_t)w*32 + i]) out |= 1u << i;
    }
  }
  bits[w] = out;
}

// ---------------- GEMM: C = A(MxK) . B(NxK)^T, K=512, tiles 128x128, BK=64 ----------------
// A16/B16: operand is f16 row-major -> global_load_lds; else f32 row-major -> reg-stage + cvt.
// MODE 0: store f16 at ((b*8+h)*ROWS + r)*64 + d  (b=m>>rshift, h=n>>6)
// MODE 1: store f16 Vt at b*524288 + gm*1024 + s  (b=n>>10, s=n&1023)
// MODE 2: store f32 out[gm*512+gn] + bias[gn]
template<int MODE, int A16, int B16, int SWZ>
__global__ __launch_bounds__(256) void gemm_f(
    const void* __restrict__ Ap, const void* __restrict__ Bp,
    void* __restrict__ Cp, const float* __restrict__ bias, int rshift)
{
  __shared__ __align__(16) u16 As[128*64];
  __shared__ __align__(16) u16 Bs[128*64];
  const int tid  = threadIdx.x;
  const int lane = tid & 63;
  const int wv   = tid >> 6;
  const int lrow = lane & 15, khi = lane >> 4;
  const int wm   = wv >> 1,  wn  = wv & 1;

  int bx = blockIdx.x, by = blockIdx.y;
  if (SWZ){
    const int nbx = gridDim.x;
    const int nwg = nbx * gridDim.y;
    const int bid = by * nbx + bx;
    const int l = (bid & 7) * (nwg >> 3) + (bid >> 3);
    by = l / nbx; bx = l - by * nbx;
  }
  const long gm0 = (long)by * 128;
  const long gn0 = (long)bx * 128;

  f32x4 acc[4][4];
  #pragma unroll
  for (int i = 0; i < 4; i++)
    #pragma unroll
    for (int j = 0; j < 4; j++) acc[i][j] = (f32x4){0.f,0.f,0.f,0.f};

  #pragma unroll 1
  for (int kk = 0; kk < 512; kk += 64){
    if (kk) __syncthreads();
    if (A16){
      const u16* ab = (const u16*)Ap;
      #pragma unroll
      for (int j = 0; j < 4; j++){
        int row = j*32 + (tid >> 3);
        GLD16(&As[j*2048 + tid*8], ab + (gm0 + row)*512 + kk + (tid & 7)*8);
      }
    } else {
      const float* ap = (const float*)Ap + (gm0 + (tid>>1))*512 + kk + (tid&1)*32;
      const int lidx = (tid>>1)*64 + (tid&1)*32;
      #pragma unroll
      for (int i = 0; i < 4; i++){
        f32x4 f0 = *(const f32x4*)(ap + i*8);
        f32x4 f1 = *(const f32x4*)(ap + i*8 + 4);
        *(half8*)&As[lidx + i*8] = cvt8(f0, f1);
      }
    }
    if (B16){
      const u16* bb = (const u16*)Bp;
      #pragma unroll
      for (int j = 0; j < 4; j++){
        int row = j*32 + (tid >> 3);
        GLD16(&Bs[j*2048 + tid*8], bb + (gn0 + row)*512 + kk + (tid & 7)*8);
      }
    } else {
      const float* bp = (const float*)Bp + (gn0 + (tid>>1))*512 + kk + (tid&1)*32;
      const int lidx = (tid>>1)*64 + (tid&1)*32;
      #pragma unroll
      for (int i = 0; i < 4; i++){
        f32x4 f0 = *(const f32x4*)(bp + i*8);
        f32x4 f1 = *(const f32x4*)(bp + i*8 + 4);
        *(half8*)&Bs[lidx + i*8] = cvt8(f0, f1);
      }
    }
    __syncthreads();

    half8 af[4][2], bf[4][2];
    #pragma unroll
    for (int mi = 0; mi < 4; mi++){
      const u16* p = &As[(wm*64 + mi*16 + lrow)*64 + khi*8];
      af[mi][0] = *(const half8*)p;
      af[mi][1] = *(const half8*)(p + 32);
    }
    #pragma unroll
    for (int ni = 0; ni < 4; ni++){
      const u16* p = &Bs[(wn*64 + ni*16 + lrow)*64 + khi*8];
      bf[ni][0] = *(const half8*)p;
      bf[ni][1] = *(const half8*)(p + 32);
    }
    #pragma unroll
    for (int mi = 0; mi < 4; mi++)
      #pragma unroll
      for (int ni = 0; ni < 4; ni++){
        acc[mi][ni] = mfma16(af[mi][0], bf[ni][0], acc[mi][ni]);
        acc[mi][ni] = mfma16(af[mi][1], bf[ni][1], acc[mi][ni]);
      }
  }

  #pragma unroll
  for (int mi = 0; mi < 4; mi++)
    #pragma unroll
    for (int ni = 0; ni < 4; ni++)
      #pragma unroll
      for (int r = 0; r < 4; r++){
        long gm = gm0 + wm*64 + mi*16 + khi*4 + r;
        long gn = gn0 + wn*64 + ni*16 + lrow;
        float v = acc[mi][ni][r];
        if (MODE == 0){
          long b  = gm >> rshift;
          long rr = gm & ((1L << rshift) - 1);
          long h  = gn >> 6, d = gn & 63;
          ((u16*)Cp)[((b*8 + h) << (rshift + 6)) + rr*64 + d] = f2h_bits(v);
        } else if (MODE == 1){
          long b = gn >> 10, s = gn & 1023;
          ((u16*)Cp)[b*524288 + gm*1024 + s] = f2h_bits(v);
        } else {
          ((float*)Cp)[gm*512 + gn] = v + bias[gn];
        }
      }
}

// ---------------- flash attention ----------------
// swizzled LDS index: element col c of row -> c ^ ((row&7)<<3); stride 64 f16 (128B rows)
__device__ __forceinline__ int swz(int row, int col){ return row*64 + (col ^ ((row & 7) << 3)); }

__global__ __launch_bounds__(256) void attn_kernel(
    const u16* __restrict__ Qb, const u16* __restrict__ Kb,
    const u16* __restrict__ Vtb, const uint32* __restrict__ bits,
    u16* __restrict__ Ctx)
{
  __shared__ __align__(16) u16 Ks[64*64];
  __shared__ __align__(16) u16 Vs[64*64];
  __shared__ __align__(16) u16 Ps[64*64];   // doubles as Q staging
  __shared__ uint32 mlds[64][2];

  const int tid  = threadIdx.x;
  const int lane = tid & 63;
  const int wv   = tid >> 6;
  const int lrow = lane & 15, khi = lane >> 4;

  const int bidx = blockIdx.x;
  const int logical = (bidx & 7) * 256 + (bidx >> 3);   // XCD swizzle: 8 p-tiles of a bh on one XCD
  const int bh = logical >> 3;
  const int p0 = (logical & 7) * 64;
  const int bb = bh >> 3;

  const u16* qp = Qb  + (size_t)bh * (P_*64) + (size_t)p0 * 64;
  const u16* kp = Kb  + (size_t)bh * (S_*64);
  const u16* vp = Vtb + (size_t)bh * (D_*S_);

  {
    int row = tid >> 2, cb = (tid & 3) * 16;
    const u16* src = qp + (size_t)row*64 + cb;
    *(half8*)&Ps[swz(row, cb)]     = *(const half8*)src;
    *(half8*)&Ps[swz(row, cb + 8)] = *(const half8*)(src + 8);
  }
  __syncthreads();
  half8 aq0, aq1;
  {
    const int row = wv*16 + lrow;
    aq0 = *(const half8*)&Ps[swz(row, khi*8)];
    aq1 = *(const half8*)&Ps[swz(row, khi*8 + 32)];
  }

  f32x4 accO[4];
  #pragma unroll
  for (int i = 0; i < 4; i++) accO[i] = (f32x4){0.f,0.f,0.f,0.f};
  float mst[4], lst[4];
  #pragma unroll
  for (int r = 0; r < 4; r++){ mst[r] = -1e30f; lst[r] = 0.f; }

  const float SCL = 0.125f * 1.44269504f;   // scale * log2(e); softmax in exp2 domain

  #pragma unroll 1
  for (int s0 = 0; s0 < S_; s0 += 64){
    __syncthreads();
    {
      int row = tid >> 2, cb = (tid & 3) * 16;
      const u16* ksrc = kp + (size_t)(s0 + row)*64 + cb;
      *(half8*)&Ks[swz(row, cb)]     = *(const half8*)ksrc;
      *(half8*)&Ks[swz(row, cb + 8)] = *(const half8*)(ksrc + 8);
      const u16* vsrc = vp + (size_t)row*S_ + s0 + cb;   // Vt rows = d, cols = s
      *(half8*)&Vs[swz(row, cb)]     = *(const half8*)vsrc;
      *(half8*)&Vs[swz(row, cb + 8)] = *(const half8*)(vsrc + 8);
    }
    if (tid < 128){
      int row = tid >> 1, wsel = tid & 1;
      mlds[row][wsel] = bits[(size_t)(bb*P_ + p0 + row)*(S_/32) + (s0 >> 5) + wsel];
    }
    __syncthreads();

    f32x4 sc[4];
    #pragma unroll
    for (int ssub = 0; ssub < 4; ssub++){
      const int r_ = ssub*16 + lrow;
      half8 bk0 = *(const half8*)&Ks[swz(r_, khi*8)];
      half8 bk1 = *(const half8*)&Ks[swz(r_, khi*8 + 32)];
      f32x4 c = (f32x4){0.f,0.f,0.f,0.f};
      c = mfma16(aq0, bk0, c);
      c = mfma16(aq1, bk1, c);
      sc[ssub] = c;
    }

    float fac[4];
    #pragma unroll
    for (int r = 0; r < 4; r++){
      const int prow = wv*16 + khi*4 + r;
      const uint32 mw0 = mlds[prow][0];
      const uint32 mw1 = mlds[prow][1];
      #pragma unroll
      for (int ssub = 0; ssub < 4; ssub++){
        int sloc = ssub*16 + lrow;
        uint32 mw = (ssub < 2) ? mw0 : mw1;
        float v = sc[ssub][r] * SCL;
        if ((mw >> (sloc & 31)) & 1u) v = -1e30f;
        sc[ssub][r] = v;
      }
      float mx = fmaxf(fmaxf(sc[0][r], sc[1][r]), fmaxf(sc[2][r], sc[3][r]));
      #pragma unroll
      for (int off = 1; off < 16; off <<= 1) mx = fmaxf(mx, __shfl_xor(mx, off));
      float mnew = fmaxf(mst[r], mx);
      fac[r] = __builtin_amdgcn_exp2f(mst[r] - mnew);
      float ts = 0.f;
      #pragma unroll
      for (int ssub = 0; ssub < 4; ssub++){
        float pv = __builtin_amdgcn_exp2f(sc[ssub][r] - mnew);
        sc[ssub][r] = pv;
        ts += pv;
      }
      #pragma unroll
      for (int off = 1; off < 16; off <<= 1) ts += __shfl_xor(ts, off);
      lst[r] = lst[r]*fac[r] + ts;
      mst[r] = mnew;
    }
    #pragma unroll
    for (int dsub = 0; dsub < 4; dsub++){
      f32x4 a = accO[dsub];
      a[0] *= fac[0]; a[1] *= fac[1]; a[2] *= fac[2]; a[3] *= fac[3];
      accO[dsub] = a;
    }

    #pragma unroll
    for (int ssub = 0; ssub < 4; ssub++)
      #pragma unroll
      for (int r = 0; r < 4; r++)
        Ps[swz(wv*16 + khi*4 + r, ssub*16 + lrow)] = f2h_bits(sc[ssub][r]);
    __syncthreads();

    half8 ap0, ap1;
    {
      const int row = wv*16 + lrow;
      ap0 = *(const half8*)&Ps[swz(row, khi*8)];
      ap1 = *(const half8*)&Ps[swz(row, khi*8 + 32)];
    }
    #pragma unroll
    for (int dsub = 0; dsub < 4; dsub++){
      const int r_ = dsub*16 + lrow;
      half8 bv0 = *(const half8*)&Vs[swz(r_, khi*8)];
      half8 bv1 = *(const half8*)&Vs[swz(r_, khi*8 + 32)];
      accO[dsub] = mfma16(ap0, bv0, accO[dsub]);
      accO[dsub] = mfma16(ap1, bv1, accO[dsub]);
    }
  }

  const int hh = bh & 7;
  #pragma unroll
  for (int r = 0; r < 4; r++){
    float inv = __builtin_amdgcn_rcpf(lst[r]);
    #pragma unroll
    for (int dsub = 0; dsub < 4; dsub++){
      int prow = p0 + wv*16 + khi*4 + r;
      float v = accO[dsub][r] * inv;
      Ctx[(size_t)(bb*P_ + prow)*E_ + hh*64 + dsub*16 + lrow] = f2h_bits(v);
    }
  }
}

extern "C" void kernel_launch(void* const* d_in, const int* in_sizes, int n_in,
                              void* d_out, int out_size, void* d_ws, size_t ws_size,
                              hipStream_t stream)
{
  const float* query = (const float*)d_in[0];
  const float* key   = (const float*)d_in[1];
  const float* value = (const float*)d_in[2];
  const void*  mask  = d_in[3];
  const float* Wq = (const float*)d_in[4];
  const float* Wk = (const float*)d_in[5];
  const float* Wv = (const float*)d_in[6];
  const float* Wo = (const float*)d_in[7];
  const float* bo = (const float*)d_in[8];

  char* ws = (char*)d_ws;
  u16*    Qb   = (u16*)(ws);                      // 16 MiB  [b*8+h][p][d] f16
  u16*    Kb   = (u16*)(ws + (16u  << 20));       // 32 MiB  [b*8+h][s][d] f16
  u16*    Vtb  = (u16*)(ws + (48u  << 20));       // 32 MiB  [b*8+h][d][s] f16
  u16*    Ctx  = (u16*)(ws + (80u  << 20));       // 16 MiB  [b*P+p][h*64+d] f16
  uint32* bits = (uint32*)(ws + (96u << 20));     // 2 MiB   packed mask bits
  int*    flag = (int*)(ws + (98u << 20));        // 4 B (ws end = R0-proven footprint)
  u16*    WqkvH= Ctx;                             // 1.5 MiB f16 Wq,Wk,Wv (Ctx region; dead by attn time)

  cvt_w_kernel<<<384, 256, 0, stream>>>(Wq, Wk, Wv, WqkvH);
  detect_mask_kernel<<<1, 256, 0, stream>>>((const uint32*)mask, flag);
  pack_mask_kernel<<<2048, 256, 0, stream>>>((const uint32*)mask, flag, bits);
  // Q: M=16384 (rshift=9), A=query f32, B=WqH f16
  gemm_f<0,0,1,1><<<dim3(4, 128), 256, 0, stream>>>((const void*)query, (const void*)(WqkvH),
                                                    (void*)Qb, nullptr, 9);
  // K: M=32768 (rshift=10)
  gemm_f<0,0,1,1><<<dim3(4, 256), 256, 0, stream>>>((const void*)key, (const void*)(WqkvH + 262144),
                                                    (void*)Kb, nullptr, 10);
  // Vt: A=WvH f16 (M=512), B=value f32 (N=32768)
  gemm_f<1,1,0,0><<<dim3(256, 4), 256, 0, stream>>>((const void*)(WqkvH + 524288), (const void*)value,
                                                    (void*)Vtb, nullptr, 0);
  attn_kernel<<<2048, 256, 0, stream>>>(Qb, Kb, Vtb, bits, Ctx);
  // out = ctx @ Wo^T + bo (fp32): A=Ctx f16 (GLD), B=Wo f32 (reg-stage+cvt)
  gemm_f<2,1,0,1><<<dim3(4, 128), 256, 0, stream>>>((const void*)Ctx, (const void*)Wo,
                                                    d_out, bo, 0);
}

// Round 8
// 430.855 us; speedup vs baseline: 1.2403x; 1.1158x over previous
//
#include <hip/hip_runtime.h>

// ManualCrossAttention: B=32,P=512,S=1024,E=512,H=8,D=64
// cvt K/V + weights -> mask pack (into d_out scratch) -> K/V/Q projections (f16 MFMA,
// global_load_lds) -> flash attn (swapped QK^T, in-register softmax, bpermute P) -> out proj.
// ws footprint: exactly 98 MiB (proven). bits+flag live in d_out until final GEMM.
#define B_  32
#define P_  512
#define S_  1024
#define E_  512
#define H_  8
#define D_  64

typedef unsigned int uint32;
typedef unsigned short u16;
typedef __attribute__((ext_vector_type(8))) _Float16 half8;
typedef __attribute__((ext_vector_type(2))) __fp16 fp16x2;
typedef __attribute__((ext_vector_type(4))) float f32x4;
typedef __attribute__((ext_vector_type(2))) uint32 u32x2;

__device__ __forceinline__ u16 f2h_bits(float f){
  _Float16 h = (_Float16)f;
  union { _Float16 h; u16 u; } cv; cv.h = h; return cv.u;
}
__device__ __forceinline__ uint32 pk16(float a, float b){
  union { fp16x2 h; uint32 u; } cv;
  cv.h = __builtin_amdgcn_cvt_pkrtz(a, b);
  return cv.u;
}
__device__ __forceinline__ half8 cvt8(f32x4 a, f32x4 b){
  half8 h;
  h[0]=(_Float16)a[0]; h[1]=(_Float16)a[1]; h[2]=(_Float16)a[2]; h[3]=(_Float16)a[3];
  h[4]=(_Float16)b[0]; h[5]=(_Float16)b[1]; h[6]=(_Float16)b[2]; h[7]=(_Float16)b[3];
  return h;
}
__device__ __forceinline__ f32x4 mfma16(half8 a, half8 b, f32x4 c){
  return __builtin_amdgcn_mfma_f32_16x16x32_f16(a, b, c, 0, 0, 0);
}
// async global->LDS, 16B per lane. LDS dest must be wave-uniform base + lane*16.
#define GLD16(ldsp, gp) __builtin_amdgcn_global_load_lds( \
    (const __attribute__((address_space(1))) void*)(gp), \
    (__attribute__((address_space(3))) void*)(ldsp), 16, 0, 0)

// ---------------- activation conversion: key,value f32 -> f16 (2^21 half8 each) --------
__global__ void cvt_kv_kernel(const float* __restrict__ key, const float* __restrict__ value,
                              u16* __restrict__ Kh, u16* __restrict__ Vh){
  size_t i = (size_t)blockIdx.x * 256 + threadIdx.x;   // 2*2^21 threads
  int region = (int)(i >> 21);
  size_t off = (i & 2097151) * 8;
  const float* s = region ? value : key;
  u16* d = region ? Vh : Kh;
  f32x4 a = *(const f32x4*)(s + off);
  f32x4 b = *(const f32x4*)(s + off + 4);
  *(half8*)(d + off) = cvt8(a, b);
}

// ---------------- weight conversion (4 x 512x512 f32 -> f16) ----------------
__global__ void cvt_w_kernel(const float* __restrict__ w0, const float* __restrict__ w1,
                             const float* __restrict__ w2, const float* __restrict__ w3,
                             u16* __restrict__ out){
  int i = blockIdx.x * 256 + threadIdx.x;          // 131072 threads, 8 elems each
  int region = i >> 15;                            // 0..3
  int off = (i & 32767) * 8;
  const float* s = (region == 0) ? w0 : (region == 1) ? w1 : (region == 2) ? w2 : w3;
  f32x4 a = *(const f32x4*)(s + off);
  f32x4 b = *(const f32x4*)(s + off + 4);
  *(half8*)(out + region * 262144 + off) = cvt8(a, b);
}

// ---------------- mask dtype detection ----------------
__global__ void detect_mask_kernel(const uint32* __restrict__ m, int* __restrict__ flag){
  __shared__ int s_gt1, s_bgt1;
  if (threadIdx.x == 0){ s_gt1 = 0; s_bgt1 = 0; }
  __syncthreads();
  int gt1 = 0, bgt1 = 0;
  for (int i = threadIdx.x; i < 4096; i += 256){
    uint32 w = m[i];
    if (w > 1u) gt1 = 1;
    if (((w)&0xffu) > 1u || ((w>>8)&0xffu) > 1u || ((w>>16)&0xffu) > 1u || ((w>>24)&0xffu) > 1u) bgt1 = 1;
  }
  if (gt1)  atomicOr(&s_gt1, 1);
  if (bgt1) atomicOr(&s_bgt1, 1);
  __syncthreads();
  if (threadIdx.x == 0) *flag = s_gt1 ? (s_bgt1 ? 2 : 1) : 0;
}

__global__ void pack_mask_kernel(const uint32* __restrict__ m, const int* __restrict__ flag,
                                 uint32* __restrict__ bits){
  const int w = blockIdx.x * 256 + threadIdx.x;   // 524288 words total
  const int f = *flag;
  uint32 out = 0u;
  if (f == 1){
    #pragma unroll
    for (int i = 0; i < 8; i++){
      uint32 v = m[(size_t)w*8 + i];
      if (v & 0x000000ffu) out |= 1u << (i*4 + 0);
      if (v & 0x0000ff00u) out |= 1u << (i*4 + 1);
      if (v & 0x00ff0000u) out |= 1u << (i*4 + 2);
      if (v & 0xff000000u) out |= 1u << (i*4 + 3);
    }
  } else {
    #pragma unroll
    for (int i = 0; i < 32; i++){
      if (m[(size_t)w*32 + i]) out |= 1u << i;
    }
  }
  bits[w] = out;
}

// ---------------- GEMM: C = A(MxK) . B(NxK)^T, K=512, tiles 128x128, BK=64 ----------------
// A16/B16: operand is f16 row-major -> global_load_lds; else f32 row-major -> reg-stage + cvt.
// MODE 0: store f16 at ((b*8+h)*ROWS + r)*64 + d  (b=m>>rshift, h=n>>6)
// MODE 1: store f16 Vt at b*524288 + gm*1024 + s  (b=n>>10, s=n&1023)
// MODE 2: store f32 out[gm*512+gn] + bias[gn]
template<int MODE, int A16, int B16, int SWZ>
__global__ __launch_bounds__(256) void gemm_f(
    const void* __restrict__ Ap, const void* __restrict__ Bp,
    void* __restrict__ Cp, const float* __restrict__ bias, int rshift)
{
  __shared__ __align__(16) u16 As[128*64];
  __shared__ __align__(16) u16 Bs[128*64];
  const int tid  = threadIdx.x;
  const int lane = tid & 63;
  const int wv   = tid >> 6;
  const int lrow = lane & 15, khi = lane >> 4;
  const int wm   = wv >> 1,  wn  = wv & 1;

  int bx = blockIdx.x, by = blockIdx.y;
  if (SWZ){
    const int nbx = gridDim.x;
    const int nwg = nbx * gridDim.y;
    const int bid = by * nbx + bx;
    const int l = (bid & 7) * (nwg >> 3) + (bid >> 3);
    by = l / nbx; bx = l - by * nbx;
  }
  const long gm0 = (long)by * 128;
  const long gn0 = (long)bx * 128;

  f32x4 acc[4][4];
  #pragma unroll
  for (int i = 0; i < 4; i++)
    #pragma unroll
    for (int j = 0; j < 4; j++) acc[i][j] = (f32x4){0.f,0.f,0.f,0.f};

  #pragma unroll 1
  for (int kk = 0; kk < 512; kk += 64){
    if (kk) __syncthreads();
    if (A16){
      const u16* ab = (const u16*)Ap;
      #pragma unroll
      for (int j = 0; j < 4; j++){
        int row = j*32 + (tid >> 3);
        GLD16(&As[j*2048 + tid*8], ab + (gm0 + row)*512 + kk + (tid & 7)*8);
      }
    } else {
      const float* ap = (const float*)Ap + (gm0 + (tid>>1))*512 + kk + (tid&1)*32;
      const int lidx = (tid>>1)*64 + (tid&1)*32;
      #pragma unroll
      for (int i = 0; i < 4; i++){
        f32x4 f0 = *(const f32x4*)(ap + i*8);
        f32x4 f1 = *(const f32x4*)(ap + i*8 + 4);
        *(half8*)&As[lidx + i*8] = cvt8(f0, f1);
      }
    }
    if (B16){
      const u16* bb = (const u16*)Bp;
      #pragma unroll
      for (int j = 0; j < 4; j++){
        int row = j*32 + (tid >> 3);
        GLD16(&Bs[j*2048 + tid*8], bb + (gn0 + row)*512 + kk + (tid & 7)*8);
      }
    } else {
      const float* bp = (const float*)Bp + (gn0 + (tid>>1))*512 + kk + (tid&1)*32;
      const int lidx = (tid>>1)*64 + (tid&1)*32;
      #pragma unroll
      for (int i = 0; i < 4; i++){
        f32x4 f0 = *(const f32x4*)(bp + i*8);
        f32x4 f1 = *(const f32x4*)(bp + i*8 + 4);
        *(half8*)&Bs[lidx + i*8] = cvt8(f0, f1);
      }
    }
    __syncthreads();

    half8 af[4][2], bf[4][2];
    #pragma unroll
    for (int mi = 0; mi < 4; mi++){
      const u16* p = &As[(wm*64 + mi*16 + lrow)*64 + khi*8];
      af[mi][0] = *(const half8*)p;
      af[mi][1] = *(const half8*)(p + 32);
    }
    #pragma unroll
    for (int ni = 0; ni < 4; ni++){
      const u16* p = &Bs[(wn*64 + ni*16 + lrow)*64 + khi*8];
      bf[ni][0] = *(const half8*)p;
      bf[ni][1] = *(const half8*)(p + 32);
    }
    #pragma unroll
    for (int mi = 0; mi < 4; mi++)
      #pragma unroll
      for (int ni = 0; ni < 4; ni++){
        acc[mi][ni] = mfma16(af[mi][0], bf[ni][0], acc[mi][ni]);
        acc[mi][ni] = mfma16(af[mi][1], bf[ni][1], acc[mi][ni]);
      }
  }

  #pragma unroll
  for (int mi = 0; mi < 4; mi++)
    #pragma unroll
    for (int ni = 0; ni < 4; ni++)
      #pragma unroll
      for (int r = 0; r < 4; r++){
        long gm = gm0 + wm*64 + mi*16 + khi*4 + r;
        long gn = gn0 + wn*64 + ni*16 + lrow;
        float v = acc[mi][ni][r];
        if (MODE == 0){
          long b  = gm >> rshift;
          long rr = gm & ((1L << rshift) - 1);
          long h  = gn >> 6, d = gn & 63;
          ((u16*)Cp)[((b*8 + h) << (rshift + 6)) + rr*64 + d] = f2h_bits(v);
        } else if (MODE == 1){
          long b = gn >> 10, s = gn & 1023;
          ((u16*)Cp)[b*524288 + gm*1024 + s] = f2h_bits(v);
        } else {
          ((float*)Cp)[gm*512 + gn] = v + bias[gn];
        }
      }
}

// ---------------- flash attention (swapped QK^T, in-register softmax) ----------------
// swizzled LDS index: element col c of row -> c ^ ((row&7)<<3); stride 64 f16 (128B rows)
__device__ __forceinline__ int swz(int row, int col){ return row*64 + (col ^ ((row & 7) << 3)); }

__global__ __launch_bounds__(256) void attn_kernel(
    const u16* __restrict__ Qb, const u16* __restrict__ Kb,
    const u16* __restrict__ Vtb, const uint32* __restrict__ bits,
    u16* __restrict__ Ctx)
{
  __shared__ __align__(16) u16 Ks[64*64];   // K tile (also Q staging pre-loop)
  __shared__ __align__(16) u16 Vs[64*64];   // Vt tile (rows=d, cols=s)
  __shared__ uint32 mlds[64][2];

  const int tid  = threadIdx.x;
  const int lane = tid & 63;
  const int wv   = tid >> 6;
  const int lrow = lane & 15, khi = lane >> 4;

  const int bidx = blockIdx.x;
  const int logical = (bidx & 7) * 256 + (bidx >> 3);   // XCD swizzle
  const int bh = logical >> 3;
  const int p0 = (logical & 7) * 64;
  const int bb = bh >> 3;

  const u16* qp = Qb  + (size_t)bh * (P_*64) + (size_t)p0 * 64;
  const u16* kp = Kb  + (size_t)bh * (S_*64);
  const u16* vp = Vtb + (size_t)bh * (D_*S_);

  // stage Q through Ks, read per-wave Q frags (q-rows wv*16+lrow)
  {
    int row = tid >> 2, cb = (tid & 3) * 16;
    const u16* src = qp + (size_t)row*64 + cb;
    *(half8*)&Ks[swz(row, cb)]     = *(const half8*)src;
    *(half8*)&Ks[swz(row, cb + 8)] = *(const half8*)(src + 8);
  }
  __syncthreads();
  half8 q_lo, q_hi;
  {
    const int row = wv*16 + lrow;
    q_lo = *(const half8*)&Ks[swz(row, khi*8)];
    q_hi = *(const half8*)&Ks[swz(row, khi*8 + 32)];
  }

  f32x4 accO[4];   // accO[dsub][r] = O^T[d=dsub*16+khi*4+r][q=lrow]
  #pragma unroll
  for (int i = 0; i < 4; i++) accO[i] = (f32x4){0.f,0.f,0.f,0.f};
  float mst = -1e30f, lst = 0.f;

  const float SCL = 0.125f * 1.44269504f;   // scale * log2(e); exp2-domain softmax
  const int srcA = (lrow + 16*((2*khi)    & 3)) << 2;  // bpermute byte addrs
  const int srcB = (lrow + 16*((2*khi + 1)& 3)) << 2;
  const bool hiH = khi >= 2;

  #pragma unroll 1
  for (int s0 = 0; s0 < S_; s0 += 64){
    __syncthreads();      // protect Ks/Vs from previous iteration's readers
    {
      int row = tid >> 2, cb = (tid & 3) * 16;
      const u16* ksrc = kp + (size_t)(s0 + row)*64 + cb;
      *(half8*)&Ks[swz(row, cb)]     = *(const half8*)ksrc;
      *(half8*)&Ks[swz(row, cb + 8)] = *(const half8*)(ksrc + 8);
      const u16* vsrc = vp + (size_t)row*S_ + s0 + cb;   // Vt rows=d, cols=s
      *(half8*)&Vs[swz(row, cb)]     = *(const half8*)vsrc;
      *(half8*)&Vs[swz(row, cb + 8)] = *(const half8*)(vsrc + 8);
    }
    if (tid < 128){
      int row = tid >> 1, wsel = tid & 1;
      mlds[row][wsel] = bits[(size_t)(bb*P_ + p0 + row)*(S_/32) + (s0 >> 5) + wsel];
    }
    __syncthreads();

    // S^T = K . Q^T : sc[ssub][r] = S[s = ssub*16 + khi*4 + r][q = lrow]
    f32x4 sc[4];
    #pragma unroll
    for (int ssub = 0; ssub < 4; ssub++){
      const int rr = ssub*16 + lrow;
      half8 k_lo = *(const half8*)&Ks[swz(rr, khi*8)];
      half8 k_hi = *(const half8*)&Ks[swz(rr, khi*8 + 32)];
      f32x4 c = (f32x4){0.f,0.f,0.f,0.f};
      c = mfma16(k_lo, q_lo, c);
      c = mfma16(k_hi, q_hi, c);
      sc[ssub] = c;
    }

    // mask + scale; row(q)-reduce is in-lane + 2 shfl (row is lane-local now)
    const uint32 mw0 = mlds[wv*16 + lrow][0];
    const uint32 mw1 = mlds[wv*16 + lrow][1];
    float mx = -1e30f;
    #pragma unroll
    for (int ssub = 0; ssub < 4; ssub++){
      const uint32 mw = (ssub < 2) ? mw0 : mw1;
      #pragma unroll
      for (int r = 0; r < 4; r++){
        const int s = ssub*16 + khi*4 + r;
        float v = sc[ssub][r] * SCL;
        if ((mw >> (s & 31)) & 1u) v = -1e30f;
        sc[ssub][r] = v;
        mx = fmaxf(mx, v);
      }
    }
    mx = fmaxf(mx, __shfl_xor(mx, 16));
    mx = fmaxf(mx, __shfl_xor(mx, 32));
    const float mnew = fmaxf(mst, mx);
    const float fac = __builtin_amdgcn_exp2f(mst - mnew);
    float ts = 0.f;
    #pragma unroll
    for (int ssub = 0; ssub < 4; ssub++)
      #pragma unroll
      for (int r = 0; r < 4; r++){
        float p = __builtin_amdgcn_exp2f(sc[ssub][r] - mnew);
        sc[ssub][r] = p;
        ts += p;
      }
    ts += __shfl_xor(ts, 16);
    ts += __shfl_xor(ts, 32);
    lst = lst * fac + ts;
    mst = mnew;
    #pragma unroll
    for (int d = 0; d < 4; d++){
      f32x4 a = accO[d];
      a[0] *= fac; a[1] *= fac; a[2] *= fac; a[3] *= fac;
      accO[d] = a;
    }

    // pack P rows to f16 pairs; redistribute to PV B-frag layout via bpermute.
    // lane owns P[q=lrow][s = ssub*16 + khi*4 + r]; target needs k=s = 8*khi + j (j=0..7).
    uint32 w00 = pk16(sc[0][0], sc[0][1]), w01 = pk16(sc[0][2], sc[0][3]);
    uint32 w10 = pk16(sc[1][0], sc[1][1]), w11 = pk16(sc[1][2], sc[1][3]);
    uint32 w20 = pk16(sc[2][0], sc[2][1]), w21 = pk16(sc[2][2], sc[2][3]);
    uint32 w30 = pk16(sc[3][0], sc[3][1]), w31 = pk16(sc[3][2], sc[3][3]);

    union { half8 h; uint32 u[4]; } plo, phi;
    {
      uint32 t0 = __builtin_amdgcn_ds_bpermute(srcA, (int)w00);
      uint32 t1 = __builtin_amdgcn_ds_bpermute(srcA, (int)w10);
      plo.u[0] = hiH ? t1 : t0;
      t0 = __builtin_amdgcn_ds_bpermute(srcA, (int)w01);
      t1 = __builtin_amdgcn_ds_bpermute(srcA, (int)w11);
      plo.u[1] = hiH ? t1 : t0;
      t0 = __builtin_amdgcn_ds_bpermute(srcB, (int)w00);
      t1 = __builtin_amdgcn_ds_bpermute(srcB, (int)w10);
      plo.u[2] = hiH ? t1 : t0;
      t0 = __builtin_amdgcn_ds_bpermute(srcB, (int)w01);
      t1 = __builtin_amdgcn_ds_bpermute(srcB, (int)w11);
      plo.u[3] = hiH ? t1 : t0;
      t0 = __builtin_amdgcn_ds_bpermute(srcA, (int)w20);
      t1 = __builtin_amdgcn_ds_bpermute(srcA, (int)w30);
      phi.u[0] = hiH ? t1 : t0;
      t0 = __builtin_amdgcn_ds_bpermute(srcA, (int)w21);
      t1 = __builtin_amdgcn_ds_bpermute(srcA, (int)w31);
      phi.u[1] = hiH ? t1 : t0;
      t0 = __builtin_amdgcn_ds_bpermute(srcB, (int)w20);
      t1 = __builtin_amdgcn_ds_bpermute(srcB, (int)w30);
      phi.u[2] = hiH ? t1 : t0;
      t0 = __builtin_amdgcn_ds_bpermute(srcB, (int)w21);
      t1 = __builtin_amdgcn_ds_bpermute(srcB, (int)w31);
      phi.u[3] = hiH ? t1 : t0;
    }

    // O^T += V^T . P^T  (A = Vt rows d, k=s; B = P^T cols q, k=s)
    #pragma unroll
    for (int dsub = 0; dsub < 4; dsub++){
      const int rr = dsub*16 + lrow;
      half8 v_lo = *(const half8*)&Vs[swz(rr, khi*8)];
      half8 v_hi = *(const half8*)&Vs[swz(rr, khi*8 + 32)];
      accO[dsub] = mfma16(v_lo, plo.h, accO[dsub]);
      accO[dsub] = mfma16(v_hi, phi.h, accO[dsub]);
    }
  }

  // epilogue: lane holds q = lrow, d = dsub*16 + khi*4 + r (4 consecutive d -> 8B stores)
  const int hh = bh & 7;
  const float inv = __builtin_amdgcn_rcpf(lst);
  const size_t base = (size_t)(bb*P_ + p0 + wv*16 + lrow) * E_ + hh*64 + khi*4;
  #pragma unroll
  for (int dsub = 0; dsub < 4; dsub++){
    u32x2 pkd;
    pkd.x = pk16(accO[dsub][0] * inv, accO[dsub][1] * inv);
    pkd.y = pk16(accO[dsub][2] * inv, accO[dsub][3] * inv);
    *(u32x2*)&Ctx[base + dsub*16] = pkd;
  }
}

extern "C" void kernel_launch(void* const* d_in, const int* in_sizes, int n_in,
                              void* d_out, int out_size, void* d_ws, size_t ws_size,
                              hipStream_t stream)
{
  const float* query = (const float*)d_in[0];
  const float* key   = (const float*)d_in[1];
  const float* value = (const float*)d_in[2];
  const void*  mask  = d_in[3];
  const float* Wq = (const float*)d_in[4];
  const float* Wk = (const float*)d_in[5];
  const float* Wv = (const float*)d_in[6];
  const float* Wo = (const float*)d_in[7];
  const float* bo = (const float*)d_in[8];

  // ws liveness plan (98 MiB total):
  //  [0,32)  Vh (f16 value)  -> dead after V-GEMM; then Qb [0,16), Ctx [16,32)
  //  [32,64) Kh (f16 key)    -> dead after K-GEMM; then Vtb [32,64)
  //  [64,96) Kb
  //  [96,98) W4h (Wq,Wk,Wv,Wo f16)
  // bits (2 MiB) + flag live in d_out (33.5 MB), overwritten by final GEMM.
  char* ws = (char*)d_ws;
  u16*    Vh   = (u16*)(ws);
  u16*    Kh   = (u16*)(ws + (32u << 20));
  u16*    Kb   = (u16*)(ws + (64u << 20));
  u16*    Vtb  = (u16*)(ws + (32u << 20));
  u16*    Qb   = (u16*)(ws);
  u16*    Ctx  = (u16*)(ws + (16u << 20));
  u16*    W4h  = (u16*)(ws + (96u << 20));
  uint32* bits = (uint32*)d_out;
  int*    flag = (int*)((char*)d_out + (2u << 20));

  cvt_kv_kernel<<<16384, 256, 0, stream>>>(key, value, Kh, Vh);
  cvt_w_kernel<<<512, 256, 0, stream>>>(Wq, Wk, Wv, Wo, W4h);
  detect_mask_kernel<<<1, 256, 0, stream>>>((const uint32*)mask, flag);
  pack_mask_kernel<<<2048, 256, 0, stream>>>((const uint32*)mask, flag, bits);
  // K: M=32768 (rshift=10), A=Kh f16, B=Wk_h f16
  gemm_f<0,1,1,1><<<dim3(4, 256), 256, 0, stream>>>((const void*)Kh, (const void*)(W4h + 262144),
                                                    (void*)Kb, nullptr, 10);
  // Vt: A=Wv_h f16 (M=512), B=Vh f16 (N=32768)
  gemm_f<1,1,1,0><<<dim3(256, 4), 256, 0, stream>>>((const void*)(W4h + 524288), (const void*)Vh,
                                                    (void*)Vtb, nullptr, 0);
  // Q: M=16384 (rshift=9), A=query f32 reg-stage, B=Wq_h f16
  gemm_f<0,0,1,1><<<dim3(4, 128), 256, 0, stream>>>((const void*)query, (const void*)W4h,
                                                    (void*)Qb, nullptr, 9);
  attn_kernel<<<2048, 256, 0, stream>>>(Qb, Kb, Vtb, bits, Ctx);
  // out = ctx @ Wo^T + bo (f32 out): A=Ctx f16, B=Wo_h f16
  gemm_f<2,1,1,1><<<dim3(4, 128), 256, 0, stream>>>((const void*)Ctx, (const void*)(W4h + 786432),
                                                    d_out, bo, 0);
}

// Round 9
// 426.269 us; speedup vs baseline: 1.2537x; 1.0108x over previous
//
#include <hip/hip_runtime.h>

// ManualCrossAttention: B=32,P=512,S=1024,E=512,H=8,D=64
// cvt weights (pre-swizzled) -> mask pack (d_out scratch) -> Q/K/V swapped-projection GEMMs
// (A=W f16 GLD16, B=act f32 reg-stage into XOR-swz LDS, packed stores, Q pre-scaled)
// -> flash attn (swapped QK^T, reg softmax, T14 prefetch, T13 defer-max, T5 setprio) -> out proj.
#define B_  32
#define P_  512
#define S_  1024
#define E_  512
#define H_  8
#define D_  64

typedef unsigned int uint32;
typedef unsigned short u16;
typedef __attribute__((ext_vector_type(8))) _Float16 half8;
typedef __attribute__((ext_vector_type(2))) __fp16 fp16x2;
typedef __attribute__((ext_vector_type(4))) float f32x4;
typedef __attribute__((ext_vector_type(2))) uint32 u32x2;

__device__ __forceinline__ u16 f2h_bits(float f){
  _Float16 h = (_Float16)f;
  union { _Float16 h; u16 u; } cv; cv.h = h; return cv.u;
}
__device__ __forceinline__ uint32 pk16(float a, float b){
  union { fp16x2 h; uint32 u; } cv;
  cv.h = __builtin_amdgcn_cvt_pkrtz(a, b);
  return cv.u;
}
__device__ __forceinline__ half8 cvt8(f32x4 a, f32x4 b){
  half8 h;
  h[0]=(_Float16)a[0]; h[1]=(_Float16)a[1]; h[2]=(_Float16)a[2]; h[3]=(_Float16)a[3];
  h[4]=(_Float16)b[0]; h[5]=(_Float16)b[1]; h[6]=(_Float16)b[2]; h[7]=(_Float16)b[3];
  return h;
}
__device__ __forceinline__ f32x4 mfma16(half8 a, half8 b, f32x4 c){
  return __builtin_amdgcn_mfma_f32_16x16x32_f16(a, b, c, 0, 0, 0);
}
// swizzled LDS index (u16 elems, 64/row): col c of row -> c ^ ((row&7)<<3)
__device__ __forceinline__ int swz(int row, int col){ return row*64 + (col ^ ((row & 7) << 3)); }
// async global->LDS, 16B per lane. LDS dest must be wave-uniform base + lane*16.
#define GLD16(ldsp, gp) __builtin_amdgcn_global_load_lds( \
    (const __attribute__((address_space(1))) void*)(gp), \
    (__attribute__((address_space(3))) void*)(ldsp), 16, 0, 0)

// ---------------- weight conversion; Wq/Wk/Wv stored pre-swizzled (for GLD16 + swz reads) ----
__global__ void cvt_w_kernel(const float* __restrict__ w0, const float* __restrict__ w1,
                             const float* __restrict__ w2, const float* __restrict__ w3,
                             u16* __restrict__ out){
  int i = blockIdx.x * 256 + threadIdx.x;          // 131072 threads, 8 elems each
  int region = i >> 15;                            // 0..3 (Wq,Wk,Wv swz; Wo linear)
  int off = (i & 32767) * 8;
  const float* s = (region == 0) ? w0 : (region == 1) ? w1 : (region == 2) ? w2 : w3;
  f32x4 a = *(const f32x4*)(s + off);
  f32x4 b = *(const f32x4*)(s + off + 4);
  int row = off >> 9;
  int k   = off & 511;                             // multiple of 8
  int ks  = (region < 3) ? ((k & ~63) | ((k & 63) ^ ((row & 7) << 3))) : k;
  *(half8*)(out + region * 262144 + row*512 + ks) = cvt8(a, b);
}

// ---------------- mask dtype detection ----------------
__global__ void detect_mask_kernel(const uint32* __restrict__ m, int* __restrict__ flag){
  __shared__ int s_gt1, s_bgt1;
  if (threadIdx.x == 0){ s_gt1 = 0; s_bgt1 = 0; }
  __syncthreads();
  int gt1 = 0, bgt1 = 0;
  for (int i = threadIdx.x; i < 4096; i += 256){
    uint32 w = m[i];
    if (w > 1u) gt1 = 1;
    if (((w)&0xffu) > 1u || ((w>>8)&0xffu) > 1u || ((w>>16)&0xffu) > 1u || ((w>>24)&0xffu) > 1u) bgt1 = 1;
  }
  if (gt1)  atomicOr(&s_gt1, 1);
  if (bgt1) atomicOr(&s_bgt1, 1);
  __syncthreads();
  if (threadIdx.x == 0) *flag = s_gt1 ? (s_bgt1 ? 2 : 1) : 0;
}

__global__ void pack_mask_kernel(const uint32* __restrict__ m, const int* __restrict__ flag,
                                 uint32* __restrict__ bits){
  const int w = blockIdx.x * 256 + threadIdx.x;   // 524288 words total
  const int f = *flag;
  uint32 out = 0u;
  if (f == 1){
    #pragma unroll
    for (int i = 0; i < 8; i++){
      uint32 v = m[(size_t)w*8 + i];
      if (v & 0x000000ffu) out |= 1u << (i*4 + 0);
      if (v & 0x0000ff00u) out |= 1u << (i*4 + 1);
      if (v & 0x00ff0000u) out |= 1u << (i*4 + 2);
      if (v & 0xff000000u) out |= 1u << (i*4 + 3);
    }
  } else {
    #pragma unroll
    for (int i = 0; i < 32; i++){
      if (m[(size_t)w*32 + i]) out |= 1u << i;
    }
  }
  bits[w] = out;
}

// ---------------- projection GEMM (swapped): C(arow,n) = Act(arow,:)·W(n,:)  ----------------
// A = W (512 x 512 f16, PRE-SWIZZLED rows) via GLD16; B = Act f32 reg-staged into swz LDS.
// MFMA: out[row = n (4 consec per lane)][col = arow (lrow)].
// MODE 0: Qb/Kb store f16 at ((b*8+h)*ROWS + rr)*64 + d, packed 8B (h=n>>6, d=n&63)
// MODE 1: Vt  store f16 at b*524288 + n*1024 + s (2B scatter)
template<int MODE>
__global__ __launch_bounds__(256) void gemm_proj(
    const u16* __restrict__ Wsz, const float* __restrict__ Act,
    u16* __restrict__ Cp, int rshift, float scale)
{
  __shared__ __align__(16) u16 As[128*64];
  __shared__ __align__(16) u16 Bs[128*64];
  const int tid  = threadIdx.x;
  const int lane = tid & 63;
  const int wv   = tid >> 6;
  const int lrow = lane & 15, khi = lane >> 4;
  const int wm   = wv >> 1,  wn  = wv & 1;

  const int nwg = gridDim.x;
  const int bid = blockIdx.x;
  const int l   = (bid & 7) * (nwg >> 3) + (bid >> 3);   // XCD chunk (nwg % 8 == 0)
  const int by  = l & 3;            // W-row tile (4 by's of one act-tile adjacent -> L2 reuse)
  const long bxL = l >> 2;          // act-row tile

  const long gm0 = (long)by * 128;  // W rows
  const long gn0 = bxL * 128;       // act rows
  const int  srow = tid >> 1, scb = (tid & 1) * 32;

  f32x4 acc[4][4];
  #pragma unroll
  for (int i = 0; i < 4; i++)
    #pragma unroll
    for (int j = 0; j < 4; j++) acc[i][j] = (f32x4){0.f,0.f,0.f,0.f};

  #pragma unroll 1
  for (int kk = 0; kk < 512; kk += 64){
    if (kk) __syncthreads();
    #pragma unroll
    for (int j = 0; j < 4; j++){
      int row = j*32 + (tid >> 3);
      GLD16(&As[j*2048 + tid*8], Wsz + (gm0 + row)*512 + kk + (tid & 7)*8);
    }
    {
      const float* bp = Act + (gn0 + srow)*512 + kk + scb;
      #pragma unroll
      for (int i = 0; i < 4; i++){
        f32x4 f0 = *(const f32x4*)(bp + i*8);
        f32x4 f1 = *(const f32x4*)(bp + i*8 + 4);
        *(half8*)&Bs[swz(srow, scb + i*8)] = cvt8(f0, f1);
      }
    }
    __syncthreads();

    half8 af[4][2], bf[4][2];
    #pragma unroll
    for (int mi = 0; mi < 4; mi++){
      const int r_ = wm*64 + mi*16 + lrow;
      af[mi][0] = *(const half8*)&As[swz(r_, khi*8)];
      af[mi][1] = *(const half8*)&As[swz(r_, khi*8 + 32)];
    }
    #pragma unroll
    for (int ni = 0; ni < 4; ni++){
      const int r_ = wn*64 + ni*16 + lrow;
      bf[ni][0] = *(const half8*)&Bs[swz(r_, khi*8)];
      bf[ni][1] = *(const half8*)&Bs[swz(r_, khi*8 + 32)];
    }
    #pragma unroll
    for (int mi = 0; mi < 4; mi++)
      #pragma unroll
      for (int ni = 0; ni < 4; ni++){
        acc[mi][ni] = mfma16(af[mi][0], bf[ni][0], acc[mi][ni]);
        acc[mi][ni] = mfma16(af[mi][1], bf[ni][1], acc[mi][ni]);
      }
  }

  #pragma unroll
  for (int mi = 0; mi < 4; mi++)
    #pragma unroll
    for (int ni = 0; ni < 4; ni++){
      f32x4 v = acc[mi][ni];
      const long arow = gn0 + wn*64 + ni*16 + lrow;
      if (MODE == 0){
        const int h  = (int)(gm0 >> 6) + wm;
        const int d0 = mi*16 + khi*4;
        const long b  = arow >> rshift;
        const long rr = arow & ((1L << rshift) - 1);
        u32x2 p;
        p.x = pk16(v[0]*scale, v[1]*scale);
        p.y = pk16(v[2]*scale, v[3]*scale);
        *(u32x2*)&Cp[(((b*8 + h) << rshift) + rr)*64 + d0] = p;
      } else {
        const long n = gm0 + wm*64 + mi*16 + khi*4;
        const long b = arow >> 10, s = arow & 1023;
        #pragma unroll
        for (int r = 0; r < 4; r++)
          Cp[b*524288 + (n + r)*1024 + s] = f2h_bits(v[r]);
      }
    }
}

// ---------------- out-projection GEMM: C = A(MxK f16)·B(NxK f16)^T + bias, f32 out --------
__global__ __launch_bounds__(256) void gemm_out(
    const u16* __restrict__ Ap, const u16* __restrict__ Bp,
    float* __restrict__ Cp, const float* __restrict__ bias)
{
  __shared__ __align__(16) u16 As[128*64];
  __shared__ __align__(16) u16 Bs[128*64];
  const int tid  = threadIdx.x;
  const int lane = tid & 63;
  const int wv   = tid >> 6;
  const int lrow = lane & 15, khi = lane >> 4;
  const int wm   = wv >> 1,  wn  = wv & 1;

  int bx = blockIdx.x, by = blockIdx.y;
  {
    const int nbx = gridDim.x;
    const int nwg = nbx * gridDim.y;
    const int bid = by * nbx + bx;
    const int l = (bid & 7) * (nwg >> 3) + (bid >> 3);
    by = l / nbx; bx = l - by * nbx;
  }
  const long gm0 = (long)by * 128;
  const long gn0 = (long)bx * 128;

  f32x4 acc[4][4];
  #pragma unroll
  for (int i = 0; i < 4; i++)
    #pragma unroll
    for (int j = 0; j < 4; j++) acc[i][j] = (f32x4){0.f,0.f,0.f,0.f};

  #pragma unroll 1
  for (int kk = 0; kk < 512; kk += 64){
    if (kk) __syncthreads();
    #pragma unroll
    for (int j = 0; j < 4; j++){
      int row = j*32 + (tid >> 3);
      GLD16(&As[j*2048 + tid*8], Ap + (gm0 + row)*512 + kk + (tid & 7)*8);
      GLD16(&Bs[j*2048 + tid*8], Bp + (gn0 + row)*512 + kk + (tid & 7)*8);
    }
    __syncthreads();

    half8 af[4][2], bf[4][2];
    #pragma unroll
    for (int mi = 0; mi < 4; mi++){
      const u16* p = &As[(wm*64 + mi*16 + lrow)*64 + khi*8];
      af[mi][0] = *(const half8*)p;
      af[mi][1] = *(const half8*)(p + 32);
    }
    #pragma unroll
    for (int ni = 0; ni < 4; ni++){
      const u16* p = &Bs[(wn*64 + ni*16 + lrow)*64 + khi*8];
      bf[ni][0] = *(const half8*)p;
      bf[ni][1] = *(const half8*)(p + 32);
    }
    #pragma unroll
    for (int mi = 0; mi < 4; mi++)
      #pragma unroll
      for (int ni = 0; ni < 4; ni++){
        acc[mi][ni] = mfma16(af[mi][0], bf[ni][0], acc[mi][ni]);
        acc[mi][ni] = mfma16(af[mi][1], bf[ni][1], acc[mi][ni]);
      }
  }

  #pragma unroll
  for (int mi = 0; mi < 4; mi++)
    #pragma unroll
    for (int ni = 0; ni < 4; ni++)
      #pragma unroll
      for (int r = 0; r < 4; r++){
        long gm = gm0 + wm*64 + mi*16 + khi*4 + r;
        long gn = gn0 + wn*64 + ni*16 + lrow;
        Cp[gm*512 + gn] = acc[mi][ni][r] + bias[gn];
      }
}

// ---------------- flash attention (swapped QK^T, reg softmax, T14 prefetch) ----------------
__global__ __launch_bounds__(256) void attn_kernel(
    const u16* __restrict__ Qb, const u16* __restrict__ Kb,
    const u16* __restrict__ Vtb, const uint32* __restrict__ bits,
    u16* __restrict__ Ctx)
{
  __shared__ __align__(16) u16 Ks[64*64];   // K tile (also Q staging pre-loop)
  __shared__ __align__(16) u16 Vs[64*64];   // Vt tile (rows=d, cols=s)

  const int tid  = threadIdx.x;
  const int lane = tid & 63;
  const int wv   = tid >> 6;
  const int lrow = lane & 15, khi = lane >> 4;

  const int bidx = blockIdx.x;
  const int logical = (bidx & 7) * 256 + (bidx >> 3);   // XCD swizzle
  const int bh = logical >> 3;
  const int p0 = (logical & 7) * 64;
  const int bb = bh >> 3;

  const u16* qp = Qb  + (size_t)bh * (P_*64) + (size_t)p0 * 64;
  const u16* kp = Kb  + (size_t)bh * (S_*64);
  const u16* vp = Vtb + (size_t)bh * (D_*S_);
  const int srow = tid >> 2, scb = (tid & 3) * 16;
  const size_t mbase = (size_t)(bb*P_ + p0 + wv*16 + lrow) * (S_/32);

  // T14: prefetch tile 0 K/V + mask into regs
  half8 kr0 = *(const half8*)(kp + (size_t)srow*64 + scb);
  half8 kr1 = *(const half8*)(kp + (size_t)srow*64 + scb + 8);
  half8 vr0 = *(const half8*)(vp + (size_t)srow*S_ + scb);
  half8 vr1 = *(const half8*)(vp + (size_t)srow*S_ + scb + 8);
  uint32 mw0 = bits[mbase], mw1 = bits[mbase + 1];

  // stage Q through Ks; read per-wave Q frags (q = wv*16+lrow); Q is pre-scaled by 0.125*log2e
  {
    const u16* src = qp + (size_t)srow*64 + scb;
    *(half8*)&Ks[swz(srow, scb)]     = *(const half8*)src;
    *(half8*)&Ks[swz(srow, scb + 8)] = *(const half8*)(src + 8);
  }
  __syncthreads();
  half8 q_lo = *(const half8*)&Ks[swz(wv*16 + lrow, khi*8)];
  half8 q_hi = *(const half8*)&Ks[swz(wv*16 + lrow, khi*8 + 32)];

  f32x4 accO[4];   // accO[dsub][r] = O^T[d=dsub*16+khi*4+r][q=lrow]
  #pragma unroll
  for (int i = 0; i < 4; i++) accO[i] = (f32x4){0.f,0.f,0.f,0.f};
  float mst = -1e30f, lst = 0.f;

  const int srcA = (lrow + 16*((2*khi)    & 3)) << 2;  // bpermute byte addrs
  const int srcB = (lrow + 16*((2*khi + 1)& 3)) << 2;
  const bool hiH = khi >= 2;

  #pragma unroll 1
  for (int t = 0; t < 16; t++){
    __syncthreads();      // prev tile readers / Q frag reads done
    *(half8*)&Ks[swz(srow, scb)]     = kr0;
    *(half8*)&Ks[swz(srow, scb + 8)] = kr1;
    *(half8*)&Vs[swz(srow, scb)]     = vr0;
    *(half8*)&Vs[swz(srow, scb + 8)] = vr1;
    __syncthreads();
    const uint32 cm0 = mw0, cm1 = mw1;
    if (t < 15){          // issue next-tile loads; latency hides under compute below
      const u16* kn = kp + (size_t)(t + 1)*4096 + (size_t)srow*64 + scb;
      kr0 = *(const half8*)kn; kr1 = *(const half8*)(kn + 8);
      const u16* vn = vp + (size_t)srow*S_ + (t + 1)*64 + scb;
      vr0 = *(const half8*)vn; vr1 = *(const half8*)(vn + 8);
      mw0 = bits[mbase + (t + 1)*2]; mw1 = bits[mbase + (t + 1)*2 + 1];
    }

    // S^T = K . Q^T : sc[ssub][r] = S[s = ssub*16 + khi*4 + r][q = lrow] (exp2 domain)
    f32x4 sc[4];
    __builtin_amdgcn_s_setprio(1);
    #pragma unroll
    for (int ssub = 0; ssub < 4; ssub++){
      const int rr = ssub*16 + lrow;
      half8 k_lo = *(const half8*)&Ks[swz(rr, khi*8)];
      half8 k_hi = *(const half8*)&Ks[swz(rr, khi*8 + 32)];
      f32x4 c = (f32x4){0.f,0.f,0.f,0.f};
      c = mfma16(k_lo, q_lo, c);
      c = mfma16(k_hi, q_hi, c);
      sc[ssub] = c;
    }
    __builtin_amdgcn_s_setprio(0);

    // mask; row(q)-reduce in-lane + 2 shfl
    float mx = -1e30f;
    #pragma unroll
    for (int ssub = 0; ssub < 4; ssub++){
      const uint32 mw = (ssub < 2) ? cm0 : cm1;
      #pragma unroll
      for (int r = 0; r < 4; r++){
        const int s = ssub*16 + khi*4 + r;
        float v = sc[ssub][r];
        if ((mw >> (s & 31)) & 1u) v = -1e30f;
        sc[ssub][r] = v;
        mx = fmaxf(mx, v);
      }
    }
    mx = fmaxf(mx, __shfl_xor(mx, 16));
    mx = fmaxf(mx, __shfl_xor(mx, 32));
    // T13 defer-max: only rescale when tile max grew past THR=8 (P bounded by 2^8, f16-safe)
    if (__any(mx - mst > 8.f)){
      const float mnew = fmaxf(mst, mx);
      const float fac = __builtin_amdgcn_exp2f(mst - mnew);
      lst *= fac;
      #pragma unroll
      for (int d = 0; d < 4; d++){
        f32x4 a = accO[d];
        a[0] *= fac; a[1] *= fac; a[2] *= fac; a[3] *= fac;
        accO[d] = a;
      }
      mst = mnew;
    }
    float ts = 0.f;
    #pragma unroll
    for (int ssub = 0; ssub < 4; ssub++)
      #pragma unroll
      for (int r = 0; r < 4; r++){
        float p = __builtin_amdgcn_exp2f(sc[ssub][r] - mst);
        sc[ssub][r] = p;
        ts += p;
      }
    ts += __shfl_xor(ts, 16);
    ts += __shfl_xor(ts, 32);
    lst += ts;

    // pack P rows to f16; redistribute to PV B-frag layout via bpermute
    uint32 w00 = pk16(sc[0][0], sc[0][1]), w01 = pk16(sc[0][2], sc[0][3]);
    uint32 w10 = pk16(sc[1][0], sc[1][1]), w11 = pk16(sc[1][2], sc[1][3]);
    uint32 w20 = pk16(sc[2][0], sc[2][1]), w21 = pk16(sc[2][2], sc[2][3]);
    uint32 w30 = pk16(sc[3][0], sc[3][1]), w31 = pk16(sc[3][2], sc[3][3]);

    union { half8 h; uint32 u[4]; } plo, phi;
    {
      uint32 t0, t1;
      t0 = __builtin_amdgcn_ds_bpermute(srcA, (int)w00);
      t1 = __builtin_amdgcn_ds_bpermute(srcA, (int)w10);
      plo.u[0] = hiH ? t1 : t0;
      t0 = __builtin_amdgcn_ds_bpermute(srcA, (int)w01);
      t1 = __builtin_amdgcn_ds_bpermute(srcA, (int)w11);
      plo.u[1] = hiH ? t1 : t0;
      t0 = __builtin_amdgcn_ds_bpermute(srcB, (int)w00);
      t1 = __builtin_amdgcn_ds_bpermute(srcB, (int)w10);
      plo.u[2] = hiH ? t1 : t0;
      t0 = __builtin_amdgcn_ds_bpermute(srcB, (int)w01);
      t1 = __builtin_amdgcn_ds_bpermute(srcB, (int)w11);
      plo.u[3] = hiH ? t1 : t0;
      t0 = __builtin_amdgcn_ds_bpermute(srcA, (int)w20);
      t1 = __builtin_amdgcn_ds_bpermute(srcA, (int)w30);
      phi.u[0] = hiH ? t1 : t0;
      t0 = __builtin_amdgcn_ds_bpermute(srcA, (int)w21);
      t1 = __builtin_amdgcn_ds_bpermute(srcA, (int)w31);
      phi.u[1] = hiH ? t1 : t0;
      t0 = __builtin_amdgcn_ds_bpermute(srcB, (int)w20);
      t1 = __builtin_amdgcn_ds_bpermute(srcB, (int)w30);
      phi.u[2] = hiH ? t1 : t0;
      t0 = __builtin_amdgcn_ds_bpermute(srcB, (int)w21);
      t1 = __builtin_amdgcn_ds_bpermute(srcB, (int)w31);
      phi.u[3] = hiH ? t1 : t0;
    }

    // O^T += V^T . P^T
    __builtin_amdgcn_s_setprio(1);
    #pragma unroll
    for (int dsub = 0; dsub < 4; dsub++){
      const int rr = dsub*16 + lrow;
      half8 v_lo = *(const half8*)&Vs[swz(rr, khi*8)];
      half8 v_hi = *(const half8*)&Vs[swz(rr, khi*8 + 32)];
      accO[dsub] = mfma16(v_lo, plo.h, accO[dsub]);
      accO[dsub] = mfma16(v_hi, phi.h, accO[dsub]);
    }
    __builtin_amdgcn_s_setprio(0);
  }

  // epilogue: lane holds q = lrow, d = dsub*16 + khi*4 + r -> packed 8B stores
  const int hh = bh & 7;
  const float inv = __builtin_amdgcn_rcpf(lst);
  const size_t base = (size_t)(bb*P_ + p0 + wv*16 + lrow) * E_ + hh*64 + khi*4;
  #pragma unroll
  for (int dsub = 0; dsub < 4; dsub++){
    u32x2 pkd;
    pkd.x = pk16(accO[dsub][0] * inv, accO[dsub][1] * inv);
    pkd.y = pk16(accO[dsub][2] * inv, accO[dsub][3] * inv);
    *(u32x2*)&Ctx[base + dsub*16] = pkd;
  }
}

extern "C" void kernel_launch(void* const* d_in, const int* in_sizes, int n_in,
                              void* d_out, int out_size, void* d_ws, size_t ws_size,
                              hipStream_t stream)
{
  const float* query = (const float*)d_in[0];
  const float* key   = (const float*)d_in[1];
  const float* value = (const float*)d_in[2];
  const void*  mask  = d_in[3];
  const float* Wq = (const float*)d_in[4];
  const float* Wk = (const float*)d_in[5];
  const float* Wv = (const float*)d_in[6];
  const float* Wo = (const float*)d_in[7];
  const float* bo = (const float*)d_in[8];

  // ws layout (98 MiB, no overlaps): Qb[0,16) Kb[16,48) Vtb[48,80) Ctx[80,96) W4h[96,98)
  // bits (2 MiB) + flag live in d_out scratch (overwritten by final GEMM).
  char* ws = (char*)d_ws;
  u16*    Qb   = (u16*)(ws);
  u16*    Kb   = (u16*)(ws + (16u << 20));
  u16*    Vtb  = (u16*)(ws + (48u << 20));
  u16*    Ctx  = (u16*)(ws + (80u << 20));
  u16*    W4h  = (u16*)(ws + (96u << 20));
  uint32* bits = (uint32*)d_out;
  int*    flag = (int*)((char*)d_out + (2u << 20));

  const float SCLQ = 0.125f * 1.44269504f;   // fold softmax scale * log2(e) into Q

  cvt_w_kernel<<<512, 256, 0, stream>>>(Wq, Wk, Wv, Wo, W4h);
  detect_mask_kernel<<<1, 256, 0, stream>>>((const uint32*)mask, flag);
  pack_mask_kernel<<<2048, 256, 0, stream>>>((const uint32*)mask, flag, bits);
  // Q: act rows 16384 (rshift=9), pre-scaled
  gemm_proj<0><<<512, 256, 0, stream>>>(W4h, query, Qb, 9, SCLQ);
  // K: act rows 32768 (rshift=10)
  gemm_proj<0><<<1024, 256, 0, stream>>>(W4h + 262144, key, Kb, 10, 1.0f);
  // Vt: act rows 32768
  gemm_proj<1><<<1024, 256, 0, stream>>>(W4h + 524288, value, Vtb, 0, 1.0f);
  attn_kernel<<<2048, 256, 0, stream>>>(Qb, Kb, Vtb, bits, Ctx);
  // out = ctx @ Wo^T + bo
  gemm_out<<<dim3(4, 128), 256, 0, stream>>>(Ctx, W4h + 786432, (float*)d_out, bo);
}